// Round 1
// baseline (322.710 us; speedup 1.0000x reference)
//
#include <hip/hip_runtime.h>
#include <math.h>

// SO(3) convolution, B_IN=16, B_OUT=8, BATCH=32, F_IN=16, F_OUT=32.
// Pipeline:
//   kA: partial 2D DFT of x (32x32 -> 15x15 freq window, m,n in -7..7)
//   kB: forward Wigner transform over b (xhat[s][z*16+f])
//   kC: yhat[s][f*32+g] = SCALING * sum_p kernel[f,g,p] * Fc[p,s]
//   kD: block spectral product zl[s=(l,m,n)][z*32+g] = sum_{k,f} xhat*conj(yhat)
//   kE: inverse Wigner + partial inverse 2D DFT (15x15 -> 16x16) + bias
// ifft2's 1/256 cancels the *256 in the reference exactly.

#define NZ 32
#define FI 16
#define FO 32
#define NB 32     // 2*B_IN
#define NBO 16    // 2*B_OUT
#define NW 15     // frequency window (-7..7)
#define NS 680    // sum_{l<8} (2l+1)^2
#define NP 24
#define SCALING 0.14433756729740643f  // 1/sqrt(48)

__device__ __constant__ int c_s0[9] = {0, 1, 10, 35, 84, 165, 286, 455, 680};

// ---------------- kA: partial forward DFT per (z,f,b) slice -----------------
__global__ void kA(const float* __restrict__ x, float2* __restrict__ xf) {
    __shared__ float  sx[32][32];
    __shared__ float2 st[32][NW];
    __shared__ float2 tw[32];   // tw[k] = e^{-2*pi*i*k/32}
    int slice = blockIdx.x;     // (z*16+f)*32 + b
    const float* xs = x + (size_t)slice * 1024;
    if (threadIdx.x < 32) {
        float s, c;
        sincosf(-2.0f * (float)M_PI * (float)threadIdx.x / 32.0f, &s, &c);
        tw[threadIdx.x] = make_float2(c, s);
    }
    for (int t = threadIdx.x; t < 1024; t += blockDim.x)
        sx[t >> 5][t & 31] = xs[t];
    __syncthreads();
    // step 1: over v ->  st[u][j], n = j-7
    for (int t = threadIdx.x; t < 32 * NW; t += blockDim.x) {
        int u = t / NW, j = t % NW, n = j - 7;
        float re = 0.f, im = 0.f;
        for (int v = 0; v < 32; v++) {
            float2 c = tw[(n * v) & 31];
            float xv = sx[u][v];
            re += xv * c.x; im += xv * c.y;
        }
        st[u][j] = make_float2(re, im);
    }
    __syncthreads();
    // step 2: over u ->  xf[i][j], m = i-7
    for (int t = threadIdx.x; t < NW * NW; t += blockDim.x) {
        int i = t / NW, j = t % NW, m = i - 7;
        float re = 0.f, im = 0.f;
        for (int u = 0; u < 32; u++) {
            float2 c = tw[(m * u) & 31];
            float2 a = st[u][j];
            re += a.x * c.x - a.y * c.y;
            im += a.x * c.y + a.y * c.x;
        }
        xf[(size_t)slice * (NW * NW) + t] = make_float2(re, im);
    }
}

// ---------------- kB: forward Wigner (reduce over b) ------------------------
__global__ void kB(const float2* __restrict__ xf, const float* __restrict__ wf,
                   float2* __restrict__ xhat) {
    int idx = blockIdx.x * blockDim.x + threadIdx.x;  // s*512 + (z*16+f)
    if (idx >= NS * 512) return;
    int s = idx >> 9, zf = idx & 511;
    int l = 0;
#pragma unroll
    for (int t = 1; t < 8; t++) if (s >= c_s0[t]) l = t;
    int K = 2 * l + 1;
    int r = s - c_s0[l];
    int i = r / K, j = r - i * K;
    int fidx = (i - l + 7) * NW + (j - l + 7);   // window position of (m,n)
    const float2* base = xf + (size_t)zf * 32 * (NW * NW) + fidx;
    float re = 0.f, im = 0.f;
    for (int b = 0; b < 32; b++) {
        float w = wf[b * NS + s];
        float2 v = base[(size_t)b * (NW * NW)];
        re += w * v.x; im += w * v.y;
    }
    xhat[(size_t)s * 512 + zf] = make_float2(re, im);
}

// ---------------- kC: yhat = (kernel*SCALING) @ Fc --------------------------
__global__ void kC(const float* __restrict__ kern, const float* __restrict__ fre,
                   const float* __restrict__ fim, float2* __restrict__ yhat) {
    int idx = blockIdx.x * blockDim.x + threadIdx.x;  // s*512 + (f*32+g)
    if (idx >= NS * 512) return;
    int s = idx >> 9, fg = idx & 511;
    float re = 0.f, im = 0.f;
    for (int p = 0; p < NP; p++) {
        float kv = kern[fg * NP + p];
        re += kv * fre[p * NS + s];
        im += kv * fim[p * NS + s];
    }
    yhat[(size_t)s * 512 + fg] = make_float2(re * SCALING, im * SCALING);
}

// ---------------- kD: zl[m,n,z,g] = sum_{k,f} xhat[m,k,z,f]*conj(yhat[n,k,f,g])
__global__ void kD(const float2* __restrict__ xhat, const float2* __restrict__ yhat,
                   float2* __restrict__ zbuf) {
    int idx = blockIdx.x * blockDim.x + threadIdx.x;  // s*1024 + (z*32+g)
    if (idx >= NS * 1024) return;
    int s = idx >> 10, zg = idx & 1023;
    int z = zg >> 5, g = zg & 31;
    int l = 0;
#pragma unroll
    for (int t = 1; t < 8; t++) if (s >= c_s0[t]) l = t;
    int K = 2 * l + 1;
    int r = s - c_s0[l];
    int m = r / K, n = r - m * K;
    float re = 0.f, im = 0.f;
    for (int k = 0; k < K; k++) {
        const float2* xa = xhat + (size_t)(c_s0[l] + m * K + k) * 512 + z * 16;
        const float2* ya = yhat + (size_t)(c_s0[l] + n * K + k) * 512 + g;
#pragma unroll
        for (int f = 0; f < 16; f++) {
            float2 a  = xa[f];
            float2 bv = ya[f * 32];
            re += a.x * bv.x + a.y * bv.y;   // a * conj(b)
            im += a.y * bv.x - a.x * bv.y;
        }
    }
    zbuf[(size_t)s * 1024 + zg] = make_float2(re, im);
}

// ---------------- kE: inverse Wigner + partial inverse DFT + bias -----------
__global__ void kE(const float2* __restrict__ zbuf, const float* __restrict__ wi,
                   const float* __restrict__ bias, float* __restrict__ out) {
    __shared__ float2 sz[NS];
    __shared__ float  swi[NS];
    __shared__ float2 ff[NW][16];
    __shared__ float2 g1[NW][16];
    __shared__ float2 tw[16];    // tw[k] = e^{+2*pi*i*k/16}
    int blk = blockIdx.x;        // (z*32+g)*16 + b
    int b = blk & 15, zg = blk >> 4, g = zg & 31;
    if (threadIdx.x < 16) {
        float s, c;
        sincosf(2.0f * (float)M_PI * (float)threadIdx.x / 16.0f, &s, &c);
        tw[threadIdx.x] = make_float2(c, s);
    }
    for (int t = threadIdx.x; t < NS; t += blockDim.x) {
        sz[t]  = zbuf[(size_t)t * 1024 + zg];
        swi[t] = wi[b * NS + t];
    }
    __syncthreads();
    // ff[m,n] = sum_{l >= max(|m|,|n|)} zl * wig_inv
    for (int t = threadIdx.x; t < NW * NW; t += blockDim.x) {
        int i = t / NW, j = t % NW;
        int m = i - 7, n = j - 7;
        int am = m < 0 ? -m : m, an = n < 0 ? -n : n;
        int lmin = am > an ? am : an;
        float re = 0.f, im = 0.f;
        for (int l = lmin; l < 8; l++) {
            int K = 2 * l + 1;
            int s = c_s0[l] + (m + l) * K + (n + l);
            float w = swi[s];
            float2 v = sz[s];
            re += w * v.x; im += w * v.y;
        }
        ff[i][j] = make_float2(re, im);
    }
    __syncthreads();
    // step 1: over n -> g1[i][v]
    for (int t = threadIdx.x; t < NW * 16; t += blockDim.x) {
        int i = t / 16, v = t & 15;
        float re = 0.f, im = 0.f;
        for (int j = 0; j < NW; j++) {
            int n = j - 7;
            float2 c = tw[(n * v) & 15];
            float2 a = ff[i][j];
            re += a.x * c.x - a.y * c.y;
            im += a.x * c.y + a.y * c.x;
        }
        g1[i][v] = make_float2(re, im);
    }
    __syncthreads();
    // step 2: over m -> out[u][v] (real part only)
    float bv = bias[g];
    for (int t = threadIdx.x; t < 256; t += blockDim.x) {
        int u = t >> 4, v = t & 15;
        float re = 0.f;
        for (int i = 0; i < NW; i++) {
            int m = i - 7;
            float2 c = tw[(m * u) & 15];
            float2 a = g1[i][v];
            re += a.x * c.x - a.y * c.y;
        }
        out[(size_t)blk * 256 + t] = re + bv;
    }
}

extern "C" void kernel_launch(void* const* d_in, const int* in_sizes, int n_in,
                              void* d_out, int out_size, void* d_ws, size_t ws_size,
                              hipStream_t stream) {
    const float* x    = (const float*)d_in[0];  // (32,16,32,32,32)
    const float* kern = (const float*)d_in[1];  // (16,32,24)
    const float* bias = (const float*)d_in[2];  // (1,32,1,1,1)
    const float* wf   = (const float*)d_in[3];  // (32,680)
    const float* wi   = (const float*)d_in[4];  // (16,680)
    const float* fre  = (const float*)d_in[5];  // (24,680)
    const float* fim  = (const float*)d_in[6];  // (24,680)
    float* out = (float*)d_out;                 // (32,32,16,16,16)

    // workspace layout (total 40,632,320 bytes)
    char* ws = (char*)d_ws;
    float2* xf   = (float2*)ws;                                  // 16384*225*8 = 29,491,200
    float2* xhat = (float2*)(ws + 29491200);                     //  680*512*8 =  2,785,280
    float2* yhat = (float2*)(ws + 29491200 + 2785280);           //  680*512*8 =  2,785,280
    float2* zbuf = (float2*)(ws + 29491200 + 2 * 2785280);       // 680*1024*8 =  5,570,560

    kA<<<16384, 256, 0, stream>>>(x, xf);
    kB<<<(NS * 512) / 256, 256, 0, stream>>>(xf, wf, xhat);
    kC<<<(NS * 512) / 256, 256, 0, stream>>>(kern, fre, fim, yhat);
    kD<<<(NS * 1024) / 256, 256, 0, stream>>>(xhat, yhat, zbuf);
    kE<<<16384, 256, 0, stream>>>(zbuf, wi, bias, out);
}

// Round 2
// 228.756 us; speedup vs baseline: 1.4107x; 1.4107x over previous
//
#include <hip/hip_runtime.h>
#include <math.h>

// SO(3) convolution, B_IN=16, B_OUT=8, BATCH=32, F_IN=16, F_OUT=32.
// Pipeline v2:
//   F1: fused partial 2D DFT (32x32 -> 15x15 window, conj-symmetry halved)
//       + forward Wigner reduction over b, accumulated in registers.
//       One block per (z,f). Eliminates the 29.5 MB xf intermediate.
//   kC: yhat[s][f*32+g] = SCALING * sum_p kernel[f,g,p] * Fc[p,s]  (unchanged)
//   kD: per-s (l,m,n) LDS-staged register-tiled complex GEMM over (k,f):
//       4 waves split k, each lane owns 4z x 4g accumulator tile.
//   kE: per-zg block: inverse Wigner + partial inverse DFT for all 16 b.

#define NS 680
#define NP 24
#define NW 15
#define SCALING 0.14433756729740643f  // 1/sqrt(48)

__device__ __constant__ int c_s0[9] = {0, 1, 10, 35, 84, 165, 286, 455, 680};

// ---------------- F1: fused partial DFT + forward Wigner --------------------
// grid 512 (= z*16+f), block 256
__global__ __launch_bounds__(256) void F1(const float* __restrict__ x,
                                          const float* __restrict__ wf,
                                          float2* __restrict__ xhat) {
    __shared__ float  sx[32 * 33];       // padded rows (kill 8-way conflicts)
    __shared__ float2 st[32][8];         // nonneg freqs n=0..7 (real input)
    __shared__ float2 xfb[NW * NW];      // only rows 7..14 (m>=0) written
    __shared__ float2 tw[32];            // e^{-2pi i k/32}
    int zf = blockIdx.x;
    int tid = threadIdx.x;
    if (tid < 32) {
        float s, c;
        sincosf(-2.0f * (float)M_PI * (float)tid / 32.0f, &s, &c);
        tw[tid] = make_float2(c, s);
    }
    // per-thread s assignments (2 or 3 of the 680 spectral slots)
    int ns = (tid < 168) ? 3 : 2;        // 680 = 2*256 + 168
    int fidx[3]; int cj[3]; float2 acc[3];
#pragma unroll
    for (int q = 0; q < 3; q++) { acc[q] = make_float2(0.f, 0.f); fidx[q] = 0; cj[q] = 0; }
    for (int q = 0; q < ns; q++) {
        int s = tid + q * 256;
        int l = 0;
#pragma unroll
        for (int t = 1; t < 8; t++) if (s >= c_s0[t]) l = t;
        int K = 2 * l + 1, r = s - c_s0[l];
        int i = r / K, j = r - i * K;
        int mw = i - l + 7, nw = j - l + 7;     // window coords 0..14
        if (mw >= 7) { fidx[q] = mw * NW + nw; cj[q] = 0; }
        else         { fidx[q] = (14 - mw) * NW + (14 - nw); cj[q] = 1; }  // conj mirror
    }
    const float* xs = x + (size_t)zf * 32768;
    for (int b = 0; b < 32; b++) {
        for (int t = tid; t < 1024; t += 256) sx[(t >> 5) * 33 + (t & 31)] = xs[b * 1024 + t];
        __syncthreads();
        {   // step 1: DFT over v, nonneg freqs only (exactly 256 items)
            int u = tid >> 3, n = tid & 7;
            float re = 0.f, im = 0.f;
            for (int v = 0; v < 32; v++) {
                float2 c = tw[(n * v) & 31];
                float xv = sx[u * 33 + v];
                re += xv * c.x; im += xv * c.y;
            }
            st[u][n] = make_float2(re, im);
        }
        __syncthreads();
        if (tid < 120) {    // step 2: DFT over u, rows m=0..7 only
            int m = tid / 15, j = tid % 15, nn = j - 7;
            float re = 0.f, im = 0.f;
            for (int u = 0; u < 32; u++) {
                float2 a = (nn >= 0) ? st[u][nn] : st[u][-nn];
                float ay = (nn >= 0) ? a.y : -a.y;
                float2 c = tw[(m * u) & 31];
                re += a.x * c.x - ay * c.y;
                im += a.x * c.y + ay * c.x;
            }
            xfb[(m + 7) * NW + j] = make_float2(re, im);
        }
        __syncthreads();
        {   // Wigner accumulate over b (registers)
            const float* wfb = wf + b * NS;
            for (int q = 0; q < ns; q++) {
                float w = wfb[tid + q * 256];
                float2 v = xfb[fidx[q]];
                float vy = cj[q] ? -v.y : v.y;
                acc[q].x += w * v.x; acc[q].y += w * vy;
            }
        }
        __syncthreads();
    }
    for (int q = 0; q < ns; q++)
        xhat[(size_t)(tid + q * 256) * 512 + zf] = acc[q];
}

// ---------------- kC: yhat = (kernel*SCALING) @ Fc --------------------------
__global__ void kC(const float* __restrict__ kern, const float* __restrict__ fre,
                   const float* __restrict__ fim, float2* __restrict__ yhat) {
    int idx = blockIdx.x * blockDim.x + threadIdx.x;  // s*512 + (f*32+g)
    if (idx >= NS * 512) return;
    int s = idx >> 9, fg = idx & 511;
    float re = 0.f, im = 0.f;
    for (int p = 0; p < NP; p++) {
        float kv = kern[fg * NP + p];
        re += kv * fre[p * NS + s];
        im += kv * fim[p * NS + s];
    }
    yhat[(size_t)s * 512 + fg] = make_float2(re * SCALING, im * SCALING);
}

// ---------------- kD: per-s tiled complex GEMM ------------------------------
// grid 680 (one per s=(l,m,n), big l first), block 256 = 4 waves.
// Wave w handles k = chunk*4 + w; lane owns 4z x 4g tile of the 32x32 output.
__global__ __launch_bounds__(256) void kD(const float2* __restrict__ xhat,
                                          const float2* __restrict__ yhat,
                                          float2* __restrict__ zbuf) {
    __shared__ float2 Xs[4][16][34];   // [kw][f][z] (+2 pad: align + banks)
    __shared__ float2 Ys[4][16][34];   // [kw][f][g]
    __shared__ float2 red[3][16][64];  // cross-wave reduce
    int s = 679 - blockIdx.x;
    int l = 0;
#pragma unroll
    for (int t = 1; t < 8; t++) if (s >= c_s0[t]) l = t;
    int K = 2 * l + 1, r = s - c_s0[l];
    int m = r / K, n = r - m * K;
    int sX0 = c_s0[l] + m * K, sY0 = c_s0[l] + n * K;
    int tid = threadIdx.x;
    int w = tid >> 6, lane = tid & 63;
    int z0 = (lane >> 3) * 4, g0 = (lane & 7) * 4;
    float2 acc[16];
#pragma unroll
    for (int i = 0; i < 16; i++) acc[i] = make_float2(0.f, 0.f);
    int nchunks = (K + 3) >> 2;
    for (int chunk = 0; chunk < nchunks; ++chunk) {
#pragma unroll
        for (int it = 0; it < 8; it++) {       // stage X: 4 k-slices, transposed
            int kw = it >> 1;
            int zf = (it & 1) * 256 + tid;
            int k = chunk * 4 + kw;
            if (k < K)
                Xs[kw][zf & 15][zf >> 4] = xhat[(size_t)(sX0 + k) * 512 + zf];
        }
#pragma unroll
        for (int it = 0; it < 8; it++) {       // stage Y: natural [f][g]
            int kw = it >> 1;
            int fg = (it & 1) * 256 + tid;
            int k = chunk * 4 + kw;
            if (k < K)
                Ys[kw][fg >> 5][fg & 31] = yhat[(size_t)(sY0 + k) * 512 + fg];
        }
        __syncthreads();
        int k = chunk * 4 + w;
        if (k < K) {
#pragma unroll
            for (int f = 0; f < 16; f++) {
                float2 xv[4], yv[4];
#pragma unroll
                for (int i = 0; i < 4; i++) xv[i] = Xs[w][f][z0 + i];
#pragma unroll
                for (int j = 0; j < 4; j++) yv[j] = Ys[w][f][g0 + j];
#pragma unroll
                for (int i = 0; i < 4; i++)
#pragma unroll
                    for (int j = 0; j < 4; j++) {
                        acc[i * 4 + j].x += xv[i].x * yv[j].x + xv[i].y * yv[j].y;
                        acc[i * 4 + j].y += xv[i].y * yv[j].x - xv[i].x * yv[j].y;
                    }
            }
        }
        __syncthreads();
    }
    // cross-wave reduction
    if (w > 0) {
#pragma unroll
        for (int i = 0; i < 16; i++) red[w - 1][i][lane] = acc[i];
    }
    __syncthreads();
    if (w == 0) {
#pragma unroll
        for (int ww = 0; ww < 3; ww++)
#pragma unroll
            for (int i = 0; i < 16; i++) {
                float2 v = red[ww][i][lane];
                acc[i].x += v.x; acc[i].y += v.y;
            }
#pragma unroll
        for (int i = 0; i < 4; i++)
#pragma unroll
            for (int j = 0; j < 4; j++)
                zbuf[(size_t)s * 1024 + (z0 + i) * 32 + (g0 + j)] = acc[i * 4 + j];
    }
}

// ---------------- kE: inverse Wigner + partial inverse DFT ------------------
// grid 1024 (one per zg), block 256; loops over all 16 beta rows.
__global__ __launch_bounds__(256) void kE(const float2* __restrict__ zbuf,
                                          const float* __restrict__ wi,
                                          const float* __restrict__ bias,
                                          float* __restrict__ out) {
    __shared__ float2 sz[NS];
    __shared__ float  swi[NS];
    __shared__ float2 ff[NW * NW];
    __shared__ float2 g1[NW][16];
    __shared__ float2 tw[16];           // e^{+2pi i k/16}
    int zg = blockIdx.x, g = zg & 31;
    int tid = threadIdx.x;
    if (tid < 16) {
        float s, c;
        sincosf(2.0f * (float)M_PI * (float)tid / 16.0f, &s, &c);
        tw[tid] = make_float2(c, s);
    }
    for (int t = tid; t < NS; t += 256) sz[t] = zbuf[(size_t)t * 1024 + zg];
    float bv = bias[g];
    for (int b = 0; b < 16; b++) {
        for (int t = tid; t < NS; t += 256) swi[t] = wi[b * NS + t];
        __syncthreads();
        if (tid < NW * NW) {   // inverse Wigner -> ff[m,n]
            int i = tid / NW, j = tid % NW;
            int m = i - 7, n = j - 7;
            int am = m < 0 ? -m : m, an = n < 0 ? -n : n;
            int lmin = am > an ? am : an;
            float re = 0.f, im = 0.f;
            for (int ll = lmin; ll < 8; ll++) {
                int KK = 2 * ll + 1;
                int s = c_s0[ll] + (m + ll) * KK + (n + ll);
                float w = swi[s];
                float2 v = sz[s];
                re += w * v.x; im += w * v.y;
            }
            ff[tid] = make_float2(re, im);
        }
        __syncthreads();
        if (tid < NW * 16) {   // inverse DFT over n
            int i = tid / 16, v = tid & 15;
            float re = 0.f, im = 0.f;
            for (int j = 0; j < NW; j++) {
                float2 c = tw[((j - 7) * v) & 15];
                float2 a = ff[i * NW + j];
                re += a.x * c.x - a.y * c.y;
                im += a.x * c.y + a.y * c.x;
            }
            g1[i][v] = make_float2(re, im);
        }
        __syncthreads();
        {   // inverse DFT over m, real part, + bias
            int u = tid >> 4, v = tid & 15;
            float re = 0.f;
            for (int i = 0; i < NW; i++) {
                float2 c = tw[((i - 7) * u) & 15];
                float2 a = g1[i][v];
                re += a.x * c.x - a.y * c.y;
            }
            out[((size_t)zg * 16 + b) * 256 + tid] = re + bv;
        }
        __syncthreads();
    }
}

extern "C" void kernel_launch(void* const* d_in, const int* in_sizes, int n_in,
                              void* d_out, int out_size, void* d_ws, size_t ws_size,
                              hipStream_t stream) {
    const float* x    = (const float*)d_in[0];  // (32,16,32,32,32)
    const float* kern = (const float*)d_in[1];  // (16,32,24)
    const float* bias = (const float*)d_in[2];  // (1,32,1,1,1)
    const float* wf   = (const float*)d_in[3];  // (32,680)
    const float* wi   = (const float*)d_in[4];  // (16,680)
    const float* fre  = (const float*)d_in[5];  // (24,680)
    const float* fim  = (const float*)d_in[6];  // (24,680)
    float* out = (float*)d_out;                 // (32,32,16,16,16)

    // workspace: xhat 2.785 MB | yhat 2.785 MB | zbuf 5.571 MB  (11.1 MB)
    char* ws = (char*)d_ws;
    float2* xhat = (float2*)ws;
    float2* yhat = (float2*)(ws + 2785280);
    float2* zbuf = (float2*)(ws + 2 * 2785280);

    F1<<<512, 256, 0, stream>>>(x, wf, xhat);
    kC<<<1360, 256, 0, stream>>>(kern, fre, fim, yhat);
    kD<<<680, 256, 0, stream>>>(xhat, yhat, zbuf);
    kE<<<1024, 256, 0, stream>>>(zbuf, wi, bias, out);
}

// Round 3
// 207.682 us; speedup vs baseline: 1.5539x; 1.1015x over previous
//
#include <hip/hip_runtime.h>
#include <math.h>

// SO(3) convolution, B_IN=16, B_OUT=8, BATCH=32, F_IN=16, F_OUT=32.
// Pipeline v3:
//   F1: fused partial 2D DFT + forward Wigner, b-loop split 8-way across
//       blocks (grid 4096), register prefetch of next b-slice. -> partials
//   kR: reduce 8 partials -> xhat[s][zf]
//   kC: yhat = SCALING * kernel @ Fc
//   kD: per-s LDS-staged register-tiled complex GEMM over (k,f)
//   kE: inverse Wigner + partial inverse DFT, b split 4-way (grid 4096)

#define NS 680
#define NP 24
#define NW 15
#define NCH 8      // F1 b-chunks
#define SCALING 0.14433756729740643f  // 1/sqrt(48)

__device__ __constant__ int c_s0[9] = {0, 1, 10, 35, 84, 165, 286, 455, 680};

// ---------------- F1: fused partial DFT + forward Wigner (partial over b) ---
// grid 4096 = chunk(8) x zf(512), block 256
__global__ __launch_bounds__(256) void F1(const float* __restrict__ x,
                                          const float* __restrict__ wf,
                                          float2* __restrict__ part) {
    __shared__ float  sx[32 * 33];
    __shared__ float2 st[32][8];
    __shared__ float2 xfb[NW * NW];
    __shared__ float2 tw[32];
    int zf = blockIdx.x & 511, chunk = blockIdx.x >> 9;
    int tid = threadIdx.x;
    if (tid < 32) {
        float s, c;
        sincosf(-2.0f * (float)M_PI * (float)tid / 32.0f, &s, &c);
        tw[tid] = make_float2(c, s);
    }
    int ns = (tid < 168) ? 3 : 2;        // 680 = 2*256 + 168
    int fidx[3]; int cj[3]; float2 acc[3];
#pragma unroll
    for (int q = 0; q < 3; q++) { acc[q] = make_float2(0.f, 0.f); fidx[q] = 0; cj[q] = 0; }
    for (int q = 0; q < ns; q++) {
        int s = tid + q * 256;
        int l = 0;
#pragma unroll
        for (int t = 1; t < 8; t++) if (s >= c_s0[t]) l = t;
        int K = 2 * l + 1, r = s - c_s0[l];
        int i = r / K, j = r - i * K;
        int mw = i - l + 7, nw = j - l + 7;
        if (mw >= 7) { fidx[q] = mw * NW + nw; cj[q] = 0; }
        else         { fidx[q] = (14 - mw) * NW + (14 - nw); cj[q] = 1; }
    }
    const float* xs = x + (size_t)zf * 32768 + chunk * 4096;  // 4 b-slices
    float pre[4];
#pragma unroll
    for (int k = 0; k < 4; k++) pre[k] = xs[tid + k * 256];
    for (int bi = 0; bi < 4; bi++) {
#pragma unroll
        for (int k = 0; k < 4; k++) {
            int t = tid + k * 256;
            sx[(t >> 5) * 33 + (t & 31)] = pre[k];
        }
        __syncthreads();
        if (bi < 3) {   // prefetch next slice; latency hides under DFT phases
            const float* xn = xs + (bi + 1) * 1024;
#pragma unroll
            for (int k = 0; k < 4; k++) pre[k] = xn[tid + k * 256];
        }
        {   // step 1: DFT over v, nonneg freqs (256 items)
            int u = tid >> 3, n = tid & 7;
            float re = 0.f, im = 0.f;
            for (int v = 0; v < 32; v++) {
                float2 c = tw[(n * v) & 31];
                float xv = sx[u * 33 + v];
                re += xv * c.x; im += xv * c.y;
            }
            st[u][n] = make_float2(re, im);
        }
        __syncthreads();
        if (tid < 120) {    // step 2: DFT over u, rows m=0..7
            int m = tid / 15, j = tid % 15, nn = j - 7;
            float re = 0.f, im = 0.f;
            for (int u = 0; u < 32; u++) {
                float2 a = (nn >= 0) ? st[u][nn] : st[u][-nn];
                float ay = (nn >= 0) ? a.y : -a.y;
                float2 c = tw[(m * u) & 31];
                re += a.x * c.x - ay * c.y;
                im += a.x * c.y + ay * c.x;
            }
            xfb[(m + 7) * NW + j] = make_float2(re, im);
        }
        __syncthreads();
        {   // Wigner accumulate
            const float* wfb = wf + (chunk * 4 + bi) * NS;
            for (int q = 0; q < ns; q++) {
                float w = wfb[tid + q * 256];
                float2 v = xfb[fidx[q]];
                float vy = cj[q] ? -v.y : v.y;
                acc[q].x += w * v.x; acc[q].y += w * vy;
            }
        }
        __syncthreads();
    }
    for (int q = 0; q < ns; q++)
        part[(size_t)chunk * (NS * 512) + (size_t)(tid + q * 256) * 512 + zf] = acc[q];
}

// ---------------- kR: reduce partials -> xhat -------------------------------
__global__ void kR(const float2* __restrict__ part, float2* __restrict__ xhat) {
    int idx = blockIdx.x * blockDim.x + threadIdx.x;
    if (idx >= NS * 512) return;
    float re = 0.f, im = 0.f;
#pragma unroll
    for (int c = 0; c < NCH; c++) {
        float2 v = part[(size_t)c * (NS * 512) + idx];
        re += v.x; im += v.y;
    }
    xhat[idx] = make_float2(re, im);
}

// ---------------- kC: yhat = (kernel*SCALING) @ Fc --------------------------
__global__ void kC(const float* __restrict__ kern, const float* __restrict__ fre,
                   const float* __restrict__ fim, float2* __restrict__ yhat) {
    int idx = blockIdx.x * blockDim.x + threadIdx.x;
    if (idx >= NS * 512) return;
    int s = idx >> 9, fg = idx & 511;
    float re = 0.f, im = 0.f;
    for (int p = 0; p < NP; p++) {
        float kv = kern[fg * NP + p];
        re += kv * fre[p * NS + s];
        im += kv * fim[p * NS + s];
    }
    yhat[(size_t)s * 512 + fg] = make_float2(re * SCALING, im * SCALING);
}

// ---------------- kD: per-s tiled complex GEMM ------------------------------
__global__ __launch_bounds__(256) void kD(const float2* __restrict__ xhat,
                                          const float2* __restrict__ yhat,
                                          float2* __restrict__ zbuf) {
    __shared__ float2 Xs[4][16][34];
    __shared__ float2 Ys[4][16][34];
    __shared__ float2 red[3][16][64];
    int s = 679 - blockIdx.x;
    int l = 0;
#pragma unroll
    for (int t = 1; t < 8; t++) if (s >= c_s0[t]) l = t;
    int K = 2 * l + 1, r = s - c_s0[l];
    int m = r / K, n = r - m * K;
    int sX0 = c_s0[l] + m * K, sY0 = c_s0[l] + n * K;
    int tid = threadIdx.x;
    int w = tid >> 6, lane = tid & 63;
    int z0 = (lane >> 3) * 4, g0 = (lane & 7) * 4;
    float2 acc[16];
#pragma unroll
    for (int i = 0; i < 16; i++) acc[i] = make_float2(0.f, 0.f);
    int nchunks = (K + 3) >> 2;
    for (int chunk = 0; chunk < nchunks; ++chunk) {
#pragma unroll
        for (int it = 0; it < 8; it++) {
            int kw = it >> 1;
            int zf = (it & 1) * 256 + tid;
            int k = chunk * 4 + kw;
            if (k < K)
                Xs[kw][zf & 15][zf >> 4] = xhat[(size_t)(sX0 + k) * 512 + zf];
        }
#pragma unroll
        for (int it = 0; it < 8; it++) {
            int kw = it >> 1;
            int fg = (it & 1) * 256 + tid;
            int k = chunk * 4 + kw;
            if (k < K)
                Ys[kw][fg >> 5][fg & 31] = yhat[(size_t)(sY0 + k) * 512 + fg];
        }
        __syncthreads();
        int k = chunk * 4 + w;
        if (k < K) {
#pragma unroll
            for (int f = 0; f < 16; f++) {
                float2 xv[4], yv[4];
#pragma unroll
                for (int i = 0; i < 4; i++) xv[i] = Xs[w][f][z0 + i];
#pragma unroll
                for (int j = 0; j < 4; j++) yv[j] = Ys[w][f][g0 + j];
#pragma unroll
                for (int i = 0; i < 4; i++)
#pragma unroll
                    for (int j = 0; j < 4; j++) {
                        acc[i * 4 + j].x += xv[i].x * yv[j].x + xv[i].y * yv[j].y;
                        acc[i * 4 + j].y += xv[i].y * yv[j].x - xv[i].x * yv[j].y;
                    }
            }
        }
        __syncthreads();
    }
    if (w > 0) {
#pragma unroll
        for (int i = 0; i < 16; i++) red[w - 1][i][lane] = acc[i];
    }
    __syncthreads();
    if (w == 0) {
#pragma unroll
        for (int ww = 0; ww < 3; ww++)
#pragma unroll
            for (int i = 0; i < 16; i++) {
                float2 v = red[ww][i][lane];
                acc[i].x += v.x; acc[i].y += v.y;
            }
#pragma unroll
        for (int i = 0; i < 4; i++)
#pragma unroll
            for (int j = 0; j < 4; j++)
                zbuf[(size_t)s * 1024 + (z0 + i) * 32 + (g0 + j)] = acc[i * 4 + j];
    }
}

// ---------------- kE: inverse Wigner + partial inverse DFT ------------------
// grid 4096 = zg(1024) x bq(4), block 256; each block does 4 beta rows.
__global__ __launch_bounds__(256) void kE(const float2* __restrict__ zbuf,
                                          const float* __restrict__ wi,
                                          const float* __restrict__ bias,
                                          float* __restrict__ out) {
    __shared__ float2 sz[NS];
    __shared__ float  swi[NS];
    __shared__ float2 ff[NW * NW];
    __shared__ float2 g1[NW][16];
    __shared__ float2 tw[16];
    int blk = blockIdx.x;
    int zg = blk >> 2, bq = blk & 3;
    int g = zg & 31;
    int tid = threadIdx.x;
    if (tid < 16) {
        float s, c;
        sincosf(2.0f * (float)M_PI * (float)tid / 16.0f, &s, &c);
        tw[tid] = make_float2(c, s);
    }
    for (int t = tid; t < NS; t += 256) sz[t] = zbuf[(size_t)t * 1024 + zg];
    float bv = bias[g];
    for (int bi = 0; bi < 4; bi++) {
        int b = bq * 4 + bi;
        for (int t = tid; t < NS; t += 256) swi[t] = wi[b * NS + t];
        __syncthreads();
        if (tid < NW * NW) {
            int i = tid / NW, j = tid % NW;
            int m = i - 7, n = j - 7;
            int am = m < 0 ? -m : m, an = n < 0 ? -n : n;
            int lmin = am > an ? am : an;
            float re = 0.f, im = 0.f;
            for (int ll = lmin; ll < 8; ll++) {
                int KK = 2 * ll + 1;
                int s = c_s0[ll] + (m + ll) * KK + (n + ll);
                float w = swi[s];
                float2 v = sz[s];
                re += w * v.x; im += w * v.y;
            }
            ff[tid] = make_float2(re, im);
        }
        __syncthreads();
        if (tid < NW * 16) {
            int i = tid / 16, v = tid & 15;
            float re = 0.f, im = 0.f;
            for (int j = 0; j < NW; j++) {
                float2 c = tw[((j - 7) * v) & 15];
                float2 a = ff[i * NW + j];
                re += a.x * c.x - a.y * c.y;
                im += a.x * c.y + a.y * c.x;
            }
            g1[i][v] = make_float2(re, im);
        }
        __syncthreads();
        {
            int u = tid >> 4, v = tid & 15;
            float re = 0.f;
            for (int i = 0; i < NW; i++) {
                float2 c = tw[((i - 7) * u) & 15];
                float2 a = g1[i][v];
                re += a.x * c.x - a.y * c.y;
            }
            out[((size_t)zg * 16 + b) * 256 + tid] = re + bv;
        }
        __syncthreads();
    }
}

extern "C" void kernel_launch(void* const* d_in, const int* in_sizes, int n_in,
                              void* d_out, int out_size, void* d_ws, size_t ws_size,
                              hipStream_t stream) {
    const float* x    = (const float*)d_in[0];
    const float* kern = (const float*)d_in[1];
    const float* bias = (const float*)d_in[2];
    const float* wf   = (const float*)d_in[3];
    const float* wi   = (const float*)d_in[4];
    const float* fre  = (const float*)d_in[5];
    const float* fim  = (const float*)d_in[6];
    float* out = (float*)d_out;

    // workspace: part 22.28 MB | xhat 2.785 MB | yhat 2.785 MB | zbuf 5.571 MB
    char* ws = (char*)d_ws;
    float2* part = (float2*)ws;
    float2* xhat = (float2*)(ws + 22282240);
    float2* yhat = (float2*)(ws + 22282240 + 2785280);
    float2* zbuf = (float2*)(ws + 22282240 + 2 * 2785280);

    F1<<<4096, 256, 0, stream>>>(x, wf, part);
    kR<<<1360, 256, 0, stream>>>(part, xhat);
    kC<<<1360, 256, 0, stream>>>(kern, fre, fim, yhat);
    kD<<<680, 256, 0, stream>>>(xhat, yhat, zbuf);
    kE<<<4096, 256, 0, stream>>>(zbuf, wi, bias, out);
}

// Round 4
// 157.774 us; speedup vs baseline: 2.0454x; 1.3163x over previous
//
#include <hip/hip_runtime.h>
#include <math.h>

// SO(3) convolution, B_IN=16, B_OUT=8, BATCH=32, F_IN=16, F_OUT=32.
// Pipeline v4:
//   A12: per-slice (z,f,b) partial 2D DFT 32x32 -> m=0..7 x n=-7..7 window
//        (conj symmetry: negative m reconstructed later). grid 16384.
//   A3 : forward Wigner reduce over b, block per zf, xf2[zf] staged in LDS.
//   kC : yhat = SCALING * kernel @ Fc
//   kD : per-s LDS-staged register-tiled complex GEMM over (k,f)
//   kE : inverse Wigner + partial inverse DFT, b split 4-way

#define NS 680
#define NP 24
#define NW 15
#define SCALING 0.14433756729740643f  // 1/sqrt(48)

__device__ __constant__ int c_s0[9] = {0, 1, 10, 35, 84, 165, 286, 455, 680};

// ---------------- A12: per-slice partial forward DFT ------------------------
// grid 16384 (= (z*16+f)*32 + b), block 256. out: xf2[slice][120] (m=0..7, n=-7..7)
__global__ __launch_bounds__(256) void A12(const float* __restrict__ x,
                                           float2* __restrict__ xf2) {
    __shared__ float  sx[32 * 36];     // [u][v] pad 36 (float4-aligned, bank-spread)
    __shared__ float2 st[32][8];       // DFT-over-v, nonneg n
    __shared__ float2 tw[32];          // e^{-2pi i k/32}
    int slice = blockIdx.x;
    int tid = threadIdx.x;
    if (tid < 32) {
        float s, c;
        sincosf(-2.0f * (float)M_PI * (float)tid / 32.0f, &s, &c);
        tw[tid] = make_float2(c, s);
    }
    {   // coalesced float4 load of the 4 KB slice
        const float4* xs = (const float4*)(x + (size_t)slice * 1024);
        float4 v4 = xs[tid];
        int u0 = tid >> 3, v0 = (tid & 7) * 4;
        *(float4*)&sx[u0 * 36 + v0] = v4;
    }
    __syncthreads();
    {   // step 1: DFT over v, n=0..7 (256 outputs, one per thread)
        int u = tid >> 3, n = tid & 7;
        float re = 0.f, im = 0.f;
#pragma unroll
        for (int v = 0; v < 32; v++) {
            float2 c = tw[(n * v) & 31];
            float xv = sx[u * 36 + v];
            re += xv * c.x; im += xv * c.y;
        }
        st[u][n] = make_float2(re, im);
    }
    __syncthreads();
    if (tid < 120) {   // step 2: DFT over u, m=0..7, n=-7..7
        int m = tid / 15, j = tid % 15, nn = j - 7;
        int an = nn < 0 ? -nn : nn;
        float sgn = nn < 0 ? -1.f : 1.f;
        float re = 0.f, im = 0.f;
#pragma unroll
        for (int u = 0; u < 32; u++) {
            float2 a = st[u][an];
            float ay = sgn * a.y;
            float2 c = tw[(m * u) & 31];
            re += a.x * c.x - ay * c.y;
            im += a.x * c.y + ay * c.x;
        }
        xf2[(size_t)slice * 120 + tid] = make_float2(re, im);
    }
}

// ---------------- A3: forward Wigner reduce over b --------------------------
// grid 512 (one per zf), block 256. xhat[s][zf]
__global__ __launch_bounds__(256) void A3(const float2* __restrict__ xf2,
                                          const float* __restrict__ wf,
                                          float2* __restrict__ xhat) {
    __shared__ float2 sxf[32 * 120];   // all b for this zf (30 KB)
    int zf = blockIdx.x, tid = threadIdx.x;
    for (int t = tid; t < 32 * 120; t += 256)
        sxf[t] = xf2[(size_t)zf * (32 * 120) + t];
    __syncthreads();
    int ns = (tid < 168) ? 3 : 2;      // 680 = 2*256 + 168
    for (int q = 0; q < ns; q++) {
        int s = tid + q * 256;
        int l = 0;
#pragma unroll
        for (int t = 1; t < 8; t++) if (s >= c_s0[t]) l = t;
        int K = 2 * l + 1, r = s - c_s0[l];
        int i = r / K, j = r - i * K;
        int mw = i - l + 7, nw = j - l + 7;          // full-window coords
        int cell, cj;
        if (mw >= 7) { cell = (mw - 7) * NW + nw; cj = 0; }
        else         { cell = (7 - mw) * NW + (14 - nw); cj = 1; }   // conj mirror
        float re = 0.f, im = 0.f;
        for (int b = 0; b < 32; b++) {
            float w = wf[b * NS + s];
            float2 v = sxf[b * 120 + cell];
            re += w * v.x;
            im += w * (cj ? -v.y : v.y);
        }
        xhat[(size_t)s * 512 + zf] = make_float2(re, im);
    }
}

// ---------------- kC: yhat = (kernel*SCALING) @ Fc --------------------------
__global__ void kC(const float* __restrict__ kern, const float* __restrict__ fre,
                   const float* __restrict__ fim, float2* __restrict__ yhat) {
    int idx = blockIdx.x * blockDim.x + threadIdx.x;
    if (idx >= NS * 512) return;
    int s = idx >> 9, fg = idx & 511;
    float re = 0.f, im = 0.f;
    for (int p = 0; p < NP; p++) {
        float kv = kern[fg * NP + p];
        re += kv * fre[p * NS + s];
        im += kv * fim[p * NS + s];
    }
    yhat[(size_t)s * 512 + fg] = make_float2(re * SCALING, im * SCALING);
}

// ---------------- kD: per-s tiled complex GEMM ------------------------------
__global__ __launch_bounds__(256) void kD(const float2* __restrict__ xhat,
                                          const float2* __restrict__ yhat,
                                          float2* __restrict__ zbuf) {
    __shared__ float2 Xs[4][16][34];
    __shared__ float2 Ys[4][16][34];
    __shared__ float2 red[3][16][64];
    int s = 679 - blockIdx.x;
    int l = 0;
#pragma unroll
    for (int t = 1; t < 8; t++) if (s >= c_s0[t]) l = t;
    int K = 2 * l + 1, r = s - c_s0[l];
    int m = r / K, n = r - m * K;
    int sX0 = c_s0[l] + m * K, sY0 = c_s0[l] + n * K;
    int tid = threadIdx.x;
    int w = tid >> 6, lane = tid & 63;
    int z0 = (lane >> 3) * 4, g0 = (lane & 7) * 4;
    float2 acc[16];
#pragma unroll
    for (int i = 0; i < 16; i++) acc[i] = make_float2(0.f, 0.f);
    int nchunks = (K + 3) >> 2;
    for (int chunk = 0; chunk < nchunks; ++chunk) {
#pragma unroll
        for (int it = 0; it < 8; it++) {
            int kw = it >> 1;
            int zf = (it & 1) * 256 + tid;
            int k = chunk * 4 + kw;
            if (k < K)
                Xs[kw][zf & 15][zf >> 4] = xhat[(size_t)(sX0 + k) * 512 + zf];
        }
#pragma unroll
        for (int it = 0; it < 8; it++) {
            int kw = it >> 1;
            int fg = (it & 1) * 256 + tid;
            int k = chunk * 4 + kw;
            if (k < K)
                Ys[kw][fg >> 5][fg & 31] = yhat[(size_t)(sY0 + k) * 512 + fg];
        }
        __syncthreads();
        int k = chunk * 4 + w;
        if (k < K) {
#pragma unroll
            for (int f = 0; f < 16; f++) {
                float2 xv[4], yv[4];
#pragma unroll
                for (int i = 0; i < 4; i++) xv[i] = Xs[w][f][z0 + i];
#pragma unroll
                for (int j = 0; j < 4; j++) yv[j] = Ys[w][f][g0 + j];
#pragma unroll
                for (int i = 0; i < 4; i++)
#pragma unroll
                    for (int j = 0; j < 4; j++) {
                        acc[i * 4 + j].x += xv[i].x * yv[j].x + xv[i].y * yv[j].y;
                        acc[i * 4 + j].y += xv[i].y * yv[j].x - xv[i].x * yv[j].y;
                    }
            }
        }
        __syncthreads();
    }
    if (w > 0) {
#pragma unroll
        for (int i = 0; i < 16; i++) red[w - 1][i][lane] = acc[i];
    }
    __syncthreads();
    if (w == 0) {
#pragma unroll
        for (int ww = 0; ww < 3; ww++)
#pragma unroll
            for (int i = 0; i < 16; i++) {
                float2 v = red[ww][i][lane];
                acc[i].x += v.x; acc[i].y += v.y;
            }
#pragma unroll
        for (int i = 0; i < 4; i++)
#pragma unroll
            for (int j = 0; j < 4; j++)
                zbuf[(size_t)s * 1024 + (z0 + i) * 32 + (g0 + j)] = acc[i * 4 + j];
    }
}

// ---------------- kE: inverse Wigner + partial inverse DFT ------------------
// grid 4096 = zg(1024) x bq(4), block 256; each block does 4 beta rows.
__global__ __launch_bounds__(256) void kE(const float2* __restrict__ zbuf,
                                          const float* __restrict__ wi,
                                          const float* __restrict__ bias,
                                          float* __restrict__ out) {
    __shared__ float2 sz[NS];
    __shared__ float  swi[NS];
    __shared__ float2 ff[NW * NW];
    __shared__ float2 g1[NW][16];
    __shared__ float2 tw[16];
    int blk = blockIdx.x;
    int zg = blk >> 2, bq = blk & 3;
    int g = zg & 31;
    int tid = threadIdx.x;
    if (tid < 16) {
        float s, c;
        sincosf(2.0f * (float)M_PI * (float)tid / 16.0f, &s, &c);
        tw[tid] = make_float2(c, s);
    }
    for (int t = tid; t < NS; t += 256) sz[t] = zbuf[(size_t)t * 1024 + zg];
    float bv = bias[g];
    for (int bi = 0; bi < 4; bi++) {
        int b = bq * 4 + bi;
        for (int t = tid; t < NS; t += 256) swi[t] = wi[b * NS + t];
        __syncthreads();
        if (tid < NW * NW) {
            int i = tid / NW, j = tid % NW;
            int m = i - 7, n = j - 7;
            int am = m < 0 ? -m : m, an = n < 0 ? -n : n;
            int lmin = am > an ? am : an;
            float re = 0.f, im = 0.f;
            for (int ll = lmin; ll < 8; ll++) {
                int KK = 2 * ll + 1;
                int s = c_s0[ll] + (m + ll) * KK + (n + ll);
                float w = swi[s];
                float2 v = sz[s];
                re += w * v.x; im += w * v.y;
            }
            ff[tid] = make_float2(re, im);
        }
        __syncthreads();
        if (tid < NW * 16) {
            int i = tid / 16, v = tid & 15;
            float re = 0.f, im = 0.f;
            for (int j = 0; j < NW; j++) {
                float2 c = tw[((j - 7) * v) & 15];
                float2 a = ff[i * NW + j];
                re += a.x * c.x - a.y * c.y;
                im += a.x * c.y + a.y * c.x;
            }
            g1[i][v] = make_float2(re, im);
        }
        __syncthreads();
        {
            int u = tid >> 4, v = tid & 15;
            float re = 0.f;
            for (int i = 0; i < NW; i++) {
                float2 c = tw[((i - 7) * u) & 15];
                float2 a = g1[i][v];
                re += a.x * c.x - a.y * c.y;
            }
            out[((size_t)zg * 16 + b) * 256 + tid] = re + bv;
        }
        __syncthreads();
    }
}

extern "C" void kernel_launch(void* const* d_in, const int* in_sizes, int n_in,
                              void* d_out, int out_size, void* d_ws, size_t ws_size,
                              hipStream_t stream) {
    const float* x    = (const float*)d_in[0];
    const float* kern = (const float*)d_in[1];
    const float* bias = (const float*)d_in[2];
    const float* wf   = (const float*)d_in[3];
    const float* wi   = (const float*)d_in[4];
    const float* fre  = (const float*)d_in[5];
    const float* fim  = (const float*)d_in[6];
    float* out = (float*)d_out;

    // workspace: xf2 15.73 MB | xhat 2.785 MB | yhat 2.785 MB | zbuf 5.571 MB
    char* ws = (char*)d_ws;
    float2* xf2  = (float2*)ws;
    float2* xhat = (float2*)(ws + 15728640);
    float2* yhat = (float2*)(ws + 15728640 + 2785280);
    float2* zbuf = (float2*)(ws + 15728640 + 2 * 2785280);

    A12<<<16384, 256, 0, stream>>>(x, xf2);
    A3<<<512, 256, 0, stream>>>(xf2, wf, xhat);
    kC<<<1360, 256, 0, stream>>>(kern, fre, fim, yhat);
    kD<<<680, 256, 0, stream>>>(xhat, yhat, zbuf);
    kE<<<4096, 256, 0, stream>>>(zbuf, wi, bias, out);
}

// Round 5
// 157.732 us; speedup vs baseline: 2.0459x; 1.0003x over previous
//
#include <hip/hip_runtime.h>
#include <math.h>

// SO(3) convolution, B_IN=16, B_OUT=8, BATCH=32, F_IN=16, F_OUT=32.
// Pipeline v5:
//   A12: per-slice (z,f,b) partial 2D DFT 32x32 -> m=0..7 x n=-7..7 window
//   A3 : forward Wigner reduce over b, block per zf, xf2[zf] staged in LDS
//   kC : yhat = SCALING * kernel @ Fc
//   kD : per-s LDS-staged register-tiled complex GEMM over (k,f)
//   kT : transpose wi -> wiT[s][b] (coalesced gather for kE2)
//   kE2: inverse Wigner + 2D inverse DFT, all 16 beta rows in parallel,
//        register-resident ff row + in-register n-DFT, 2 barriers/block.

#define NS 680
#define NP 24
#define NW 15
#define SCALING 0.14433756729740643f  // 1/sqrt(48)

__device__ __constant__ int c_s0[9] = {0, 1, 10, 35, 84, 165, 286, 455, 680};

// ---------------- A12: per-slice partial forward DFT ------------------------
__global__ __launch_bounds__(256) void A12(const float* __restrict__ x,
                                           float2* __restrict__ xf2) {
    __shared__ float  sx[32 * 36];
    __shared__ float2 st[32][8];
    __shared__ float2 tw[32];
    int slice = blockIdx.x;
    int tid = threadIdx.x;
    if (tid < 32) {
        float s, c;
        sincosf(-2.0f * (float)M_PI * (float)tid / 32.0f, &s, &c);
        tw[tid] = make_float2(c, s);
    }
    {
        const float4* xs = (const float4*)(x + (size_t)slice * 1024);
        float4 v4 = xs[tid];
        int u0 = tid >> 3, v0 = (tid & 7) * 4;
        *(float4*)&sx[u0 * 36 + v0] = v4;
    }
    __syncthreads();
    {
        int u = tid >> 3, n = tid & 7;
        float re = 0.f, im = 0.f;
#pragma unroll
        for (int v = 0; v < 32; v++) {
            float2 c = tw[(n * v) & 31];
            float xv = sx[u * 36 + v];
            re += xv * c.x; im += xv * c.y;
        }
        st[u][n] = make_float2(re, im);
    }
    __syncthreads();
    if (tid < 120) {
        int m = tid / 15, j = tid % 15, nn = j - 7;
        int an = nn < 0 ? -nn : nn;
        float sgn = nn < 0 ? -1.f : 1.f;
        float re = 0.f, im = 0.f;
#pragma unroll
        for (int u = 0; u < 32; u++) {
            float2 a = st[u][an];
            float ay = sgn * a.y;
            float2 c = tw[(m * u) & 31];
            re += a.x * c.x - ay * c.y;
            im += a.x * c.y + ay * c.x;
        }
        xf2[(size_t)slice * 120 + tid] = make_float2(re, im);
    }
}

// ---------------- A3: forward Wigner reduce over b --------------------------
__global__ __launch_bounds__(256) void A3(const float2* __restrict__ xf2,
                                          const float* __restrict__ wf,
                                          float2* __restrict__ xhat) {
    __shared__ float2 sxf[32 * 120];
    int zf = blockIdx.x, tid = threadIdx.x;
    for (int t = tid; t < 32 * 120; t += 256)
        sxf[t] = xf2[(size_t)zf * (32 * 120) + t];
    __syncthreads();
    int ns = (tid < 168) ? 3 : 2;
    for (int q = 0; q < ns; q++) {
        int s = tid + q * 256;
        int l = 0;
#pragma unroll
        for (int t = 1; t < 8; t++) if (s >= c_s0[t]) l = t;
        int K = 2 * l + 1, r = s - c_s0[l];
        int i = r / K, j = r - i * K;
        int mw = i - l + 7, nw = j - l + 7;
        int cell, cj;
        if (mw >= 7) { cell = (mw - 7) * NW + nw; cj = 0; }
        else         { cell = (7 - mw) * NW + (14 - nw); cj = 1; }
        float re = 0.f, im = 0.f;
        for (int b = 0; b < 32; b++) {
            float w = wf[b * NS + s];
            float2 v = sxf[b * 120 + cell];
            re += w * v.x;
            im += w * (cj ? -v.y : v.y);
        }
        xhat[(size_t)s * 512 + zf] = make_float2(re, im);
    }
}

// ---------------- kC: yhat = (kernel*SCALING) @ Fc --------------------------
__global__ void kC(const float* __restrict__ kern, const float* __restrict__ fre,
                   const float* __restrict__ fim, float2* __restrict__ yhat) {
    int idx = blockIdx.x * blockDim.x + threadIdx.x;
    if (idx >= NS * 512) return;
    int s = idx >> 9, fg = idx & 511;
    float re = 0.f, im = 0.f;
    for (int p = 0; p < NP; p++) {
        float kv = kern[fg * NP + p];
        re += kv * fre[p * NS + s];
        im += kv * fim[p * NS + s];
    }
    yhat[(size_t)s * 512 + fg] = make_float2(re * SCALING, im * SCALING);
}

// ---------------- kD: per-s tiled complex GEMM ------------------------------
__global__ __launch_bounds__(256) void kD(const float2* __restrict__ xhat,
                                          const float2* __restrict__ yhat,
                                          float2* __restrict__ zbuf) {
    __shared__ float2 Xs[4][16][34];
    __shared__ float2 Ys[4][16][34];
    __shared__ float2 red[3][16][64];
    int s = 679 - blockIdx.x;
    int l = 0;
#pragma unroll
    for (int t = 1; t < 8; t++) if (s >= c_s0[t]) l = t;
    int K = 2 * l + 1, r = s - c_s0[l];
    int m = r / K, n = r - m * K;
    int sX0 = c_s0[l] + m * K, sY0 = c_s0[l] + n * K;
    int tid = threadIdx.x;
    int w = tid >> 6, lane = tid & 63;
    int z0 = (lane >> 3) * 4, g0 = (lane & 7) * 4;
    float2 acc[16];
#pragma unroll
    for (int i = 0; i < 16; i++) acc[i] = make_float2(0.f, 0.f);
    int nchunks = (K + 3) >> 2;
    for (int chunk = 0; chunk < nchunks; ++chunk) {
#pragma unroll
        for (int it = 0; it < 8; it++) {
            int kw = it >> 1;
            int zf = (it & 1) * 256 + tid;
            int k = chunk * 4 + kw;
            if (k < K)
                Xs[kw][zf & 15][zf >> 4] = xhat[(size_t)(sX0 + k) * 512 + zf];
        }
#pragma unroll
        for (int it = 0; it < 8; it++) {
            int kw = it >> 1;
            int fg = (it & 1) * 256 + tid;
            int k = chunk * 4 + kw;
            if (k < K)
                Ys[kw][fg >> 5][fg & 31] = yhat[(size_t)(sY0 + k) * 512 + fg];
        }
        __syncthreads();
        int k = chunk * 4 + w;
        if (k < K) {
#pragma unroll
            for (int f = 0; f < 16; f++) {
                float2 xv[4], yv[4];
#pragma unroll
                for (int i = 0; i < 4; i++) xv[i] = Xs[w][f][z0 + i];
#pragma unroll
                for (int j = 0; j < 4; j++) yv[j] = Ys[w][f][g0 + j];
#pragma unroll
                for (int i = 0; i < 4; i++)
#pragma unroll
                    for (int j = 0; j < 4; j++) {
                        acc[i * 4 + j].x += xv[i].x * yv[j].x + xv[i].y * yv[j].y;
                        acc[i * 4 + j].y += xv[i].y * yv[j].x - xv[i].x * yv[j].y;
                    }
            }
        }
        __syncthreads();
    }
    if (w > 0) {
#pragma unroll
        for (int i = 0; i < 16; i++) red[w - 1][i][lane] = acc[i];
    }
    __syncthreads();
    if (w == 0) {
#pragma unroll
        for (int ww = 0; ww < 3; ww++)
#pragma unroll
            for (int i = 0; i < 16; i++) {
                float2 v = red[ww][i][lane];
                acc[i].x += v.x; acc[i].y += v.y;
            }
#pragma unroll
        for (int i = 0; i < 4; i++)
#pragma unroll
            for (int j = 0; j < 4; j++)
                zbuf[(size_t)s * 1024 + (z0 + i) * 32 + (g0 + j)] = acc[i * 4 + j];
    }
}

// ---------------- kT: wi -> wiT[s][b] ---------------------------------------
__global__ void kT(const float* __restrict__ wi, float* __restrict__ wiT) {
    int idx = blockIdx.x * blockDim.x + threadIdx.x;
    if (idx >= NS * 16) return;
    int s = idx >> 4, b = idx & 15;
    wiT[s * 16 + b] = wi[b * NS + s];
}

// ---------------- kE2: inverse Wigner + inverse 2D DFT, all b parallel ------
// grid 1024 (one per zg), block 256 = 16 b x 16 rows. 2 barriers.
__global__ __launch_bounds__(256) void kE2(const float2* __restrict__ zbuf,
                                           const float* __restrict__ wiT,
                                           const float* __restrict__ bias,
                                           float* __restrict__ out) {
    __shared__ float2 sz[NS];
    __shared__ float2 g1[16][241];   // [b][m*16+v], pad 241 (482 words % 32 = 2)
    __shared__ float2 tw[16];        // e^{+2pi i k/16}
    int zg = blockIdx.x, g = zg & 31;
    int tid = threadIdx.x;
    int b = tid & 15, row = tid >> 4;
    if (tid < 16) {
        float s, c;
        sincosf(2.0f * (float)M_PI * (float)tid / 16.0f, &s, &c);
        tw[tid] = make_float2(c, s);
    }
    for (int t = tid; t < NS; t += 256) sz[t] = zbuf[(size_t)t * 1024 + zg];
    __syncthreads();
    if (row < 15) {                  // thread (b, m): Wigner row + n-DFT in regs
        int mm = row - 7;
        int am = mm < 0 ? -mm : mm;
        float2 ff[15];
#pragma unroll
        for (int n = 0; n < 15; n++) {
            int nn = n - 7;
            int an = nn < 0 ? -nn : nn;
            int lmin = am > an ? am : an;
            float re = 0.f, im = 0.f;
            for (int l = lmin; l < 8; l++) {
                int K = 2 * l + 1;
                int s = c_s0[l] + (mm + l) * K + (nn + l);
                float w = wiT[s * 16 + b];
                float2 v = sz[s];
                re += w * v.x; im += w * v.y;
            }
            ff[n] = make_float2(re, im);
        }
#pragma unroll
        for (int v = 0; v < 16; v++) {   // n-DFT (in-register)
            float re = 0.f, im = 0.f;
#pragma unroll
            for (int n = 0; n < 15; n++) {
                float2 c = tw[((n - 7) * v) & 15];
                float2 a = ff[n];
                re += a.x * c.x - a.y * c.y;
                im += a.x * c.y + a.y * c.x;
            }
            g1[b][row * 16 + v] = make_float2(re, im);
        }
    }
    __syncthreads();
    {                                // thread (b, u): m-DFT, real part, write
        int u = row;
        float o[16];
#pragma unroll
        for (int v = 0; v < 16; v++) o[v] = 0.f;
        for (int m = 0; m < 15; m++) {
            float2 c = tw[((m - 7) * u) & 15];
#pragma unroll
            for (int v = 0; v < 16; v++) {
                float2 a = g1[b][m * 16 + v];
                o[v] += a.x * c.x - a.y * c.y;
            }
        }
        float bv = bias[g];
        float* ob = out + ((size_t)zg * 16 + b) * 256 + u * 16;
#pragma unroll
        for (int v = 0; v < 16; v += 4)
            *(float4*)&ob[v] = make_float4(o[v] + bv, o[v + 1] + bv, o[v + 2] + bv, o[v + 3] + bv);
    }
}

extern "C" void kernel_launch(void* const* d_in, const int* in_sizes, int n_in,
                              void* d_out, int out_size, void* d_ws, size_t ws_size,
                              hipStream_t stream) {
    const float* x    = (const float*)d_in[0];
    const float* kern = (const float*)d_in[1];
    const float* bias = (const float*)d_in[2];
    const float* wf   = (const float*)d_in[3];
    const float* wi   = (const float*)d_in[4];
    const float* fre  = (const float*)d_in[5];
    const float* fim  = (const float*)d_in[6];
    float* out = (float*)d_out;

    // workspace: xf2 15.73 MB | xhat 2.785 MB | yhat 2.785 MB | zbuf 5.571 MB | wiT 43.5 KB
    char* ws = (char*)d_ws;
    float2* xf2  = (float2*)ws;
    float2* xhat = (float2*)(ws + 15728640);
    float2* yhat = (float2*)(ws + 15728640 + 2785280);
    float2* zbuf = (float2*)(ws + 15728640 + 2 * 2785280);
    float*  wiT  = (float*)(ws + 15728640 + 2 * 2785280 + 5570560);

    A12<<<16384, 256, 0, stream>>>(x, xf2);
    A3<<<512, 256, 0, stream>>>(xf2, wf, xhat);
    kC<<<1360, 256, 0, stream>>>(kern, fre, fim, yhat);
    kT<<<43, 256, 0, stream>>>(wi, wiT);
    kD<<<680, 256, 0, stream>>>(xhat, yhat, zbuf);
    kE2<<<1024, 256, 0, stream>>>(zbuf, wiT, bias, out);
}

// Round 7
// 125.041 us; speedup vs baseline: 2.5808x; 1.2614x over previous
//
#include <hip/hip_runtime.h>
#include <math.h>

// SO(3) convolution, B_IN=16, B_OUT=8, BATCH=32, F_IN=16, F_OUT=32.
// Pipeline v6.1 (Hermitian-symmetry halved spectral pipeline; kD geometry fix):
//   A12: per-slice (z,f,b) partial 2D DFT 32x32 -> m=0..7 x n=-7..7 window
//   kT2: transpose wf/wi into wfT[s'][b], wiT[s'][b] for the RESTRICTED
//        s'-set (m>=0 rows only, 372 entries)
//   kC : yhat = SCALING * kernel @ Fc  (full 680 set)
//   A3 : forward Wigner reduce over b -> xhat'[s'][zf], restricted set
//   kD : per-s' complex GEMM zl[m>=0,n] = sum_{k,f} xhat*conj(yhat)
//        thread t owns (zl=t>>4, g={2(t&15), 2(t&15)+1}); exact 16z x 32g cover.
//   kE2: inverse Wigner (m>=0) + n-DFT + Hermitian-paired m-DFT:
//        out[u,v] = h0[v] + 2*sum_{m=1..7} Re(e^{2pi i mu/16} h_m[v])

#define NS 680      // full spectral size
#define NR 372      // restricted (m>=0) spectral size
#define NP 24
#define NW 15
#define SCALING 0.14433756729740643f  // 1/sqrt(48)

__device__ __constant__ int c_s0[9] = {0, 1, 10, 35, 84, 165, 286, 455, 680};
__device__ __constant__ int c_o[9]  = {0, 1, 7, 22, 50, 95, 161, 252, 372};

// ---------------- A12: per-slice partial forward DFT ------------------------
__global__ __launch_bounds__(256) void A12(const float* __restrict__ x,
                                           float2* __restrict__ xf2) {
    __shared__ float  sx[32 * 36];
    __shared__ float2 st[32][8];
    __shared__ float2 tw[32];
    int slice = blockIdx.x;
    int tid = threadIdx.x;
    if (tid < 32) {
        float s, c;
        sincosf(-2.0f * (float)M_PI * (float)tid / 32.0f, &s, &c);
        tw[tid] = make_float2(c, s);
    }
    {
        const float4* xs = (const float4*)(x + (size_t)slice * 1024);
        float4 v4 = xs[tid];
        int u0 = tid >> 3, v0 = (tid & 7) * 4;
        *(float4*)&sx[u0 * 36 + v0] = v4;
    }
    __syncthreads();
    {
        int u = tid >> 3, n = tid & 7;
        float re = 0.f, im = 0.f;
#pragma unroll
        for (int v = 0; v < 32; v++) {
            float2 c = tw[(n * v) & 31];
            float xv = sx[u * 36 + v];
            re += xv * c.x; im += xv * c.y;
        }
        st[u][n] = make_float2(re, im);
    }
    __syncthreads();
    if (tid < 120) {
        int m = tid / 15, j = tid % 15, nn = j - 7;
        int an = nn < 0 ? -nn : nn;
        float sgn = nn < 0 ? -1.f : 1.f;
        float re = 0.f, im = 0.f;
#pragma unroll
        for (int u = 0; u < 32; u++) {
            float2 a = st[u][an];
            float ay = sgn * a.y;
            float2 c = tw[(m * u) & 31];
            re += a.x * c.x - ay * c.y;
            im += a.x * c.y + ay * c.x;
        }
        xf2[(size_t)slice * 120 + tid] = make_float2(re, im);
    }
}

// ---------------- kT2: build wfT[s'][32] and wiT[s'][16] --------------------
__global__ void kT2(const float* __restrict__ wf, const float* __restrict__ wi,
                    float* __restrict__ wfT, float* __restrict__ wiT) {
    int idx = blockIdx.x * blockDim.x + threadIdx.x;
    int sp, b, isWi;
    if (idx < NR * 32) { sp = idx >> 5; b = idx & 31; isWi = 0; }
    else {
        int j = idx - NR * 32;
        if (j >= NR * 16) return;
        sp = j >> 4; b = j & 15; isWi = 1;
    }
    int l = 0;
#pragma unroll
    for (int t = 1; t < 8; t++) if (sp >= c_o[t]) l = t;
    int K = 2 * l + 1, r = sp - c_o[l];
    int m = r / K, jn = r - m * K;
    int sf = c_s0[l] + (m + l) * K + jn;
    if (isWi) wiT[sp * 16 + b] = wi[b * NS + sf];
    else      wfT[sp * 32 + b] = wf[b * NS + sf];
}

// ---------------- kC: yhat = (kernel*SCALING) @ Fc (full set) ---------------
__global__ void kC(const float* __restrict__ kern, const float* __restrict__ fre,
                   const float* __restrict__ fim, float2* __restrict__ yhat) {
    int idx = blockIdx.x * blockDim.x + threadIdx.x;
    if (idx >= NS * 512) return;
    int s = idx >> 9, fg = idx & 511;
    float re = 0.f, im = 0.f;
    for (int p = 0; p < NP; p++) {
        float kv = kern[fg * NP + p];
        re += kv * fre[p * NS + s];
        im += kv * fim[p * NS + s];
    }
    yhat[(size_t)s * 512 + fg] = make_float2(re * SCALING, im * SCALING);
}

// ---------------- A3: forward Wigner reduce over b (restricted) -------------
// grid 1024 = zf(512) x s-half(2), block 256
__global__ __launch_bounds__(256) void A3(const float2* __restrict__ xf2,
                                          const float* __restrict__ wfT,
                                          float2* __restrict__ xhat) {
    __shared__ float2 sxf[32 * 120];
    int zf = blockIdx.x >> 1, sh = blockIdx.x & 1;
    int tid = threadIdx.x;
    for (int t = tid; t < 32 * 120; t += 256)
        sxf[t] = xf2[(size_t)zf * (32 * 120) + t];
    __syncthreads();
    if (tid < 186) {
        int sp = sh * 186 + tid;
        int l = 0;
#pragma unroll
        for (int t = 1; t < 8; t++) if (sp >= c_o[t]) l = t;
        int K = 2 * l + 1, r = sp - c_o[l];
        int m = r / K, jn = r - m * K;
        int cell = m * 15 + (jn - l + 7);
        const float4* wp = (const float4*)(wfT + sp * 32);
        const float2* xp = sxf + cell;
        float re = 0.f, im = 0.f;
#pragma unroll
        for (int q = 0; q < 8; q++) {
            float4 w4 = wp[q];
            float2 v0 = xp[(q * 4 + 0) * 120];
            float2 v1 = xp[(q * 4 + 1) * 120];
            float2 v2 = xp[(q * 4 + 2) * 120];
            float2 v3 = xp[(q * 4 + 3) * 120];
            re += w4.x * v0.x + w4.y * v1.x + w4.z * v2.x + w4.w * v3.x;
            im += w4.x * v0.y + w4.y * v1.y + w4.z * v2.y + w4.w * v3.y;
        }
        xhat[(size_t)sp * 512 + zf] = make_float2(re, im);
    }
}

// ---------------- kD: per-s' complex GEMM -----------------------------------
// grid 744 = s'(372) x z-half(2), block 256.
// thread t: zl = t>>4 (0..15 local z), g0 = (t&15)*2 (covers all 32 g).
__global__ __launch_bounds__(256) void kD(const float2* __restrict__ xhat,
                                          const float2* __restrict__ yhat,
                                          float2* __restrict__ zbuf) {
    __shared__ float2 Xs[4][16][18];   // [kw][f][z-local]
    __shared__ float2 Ys[4][16][34];   // [kw][f][g]
    int sp = 371 - (blockIdx.x >> 1);
    int zh = blockIdx.x & 1;
    int l = 0;
#pragma unroll
    for (int t = 1; t < 8; t++) if (sp >= c_o[t]) l = t;
    int K = 2 * l + 1, r = sp - c_o[l];
    int m = r / K, jn = r - m * K;
    int sX0 = c_o[l] + m * K;            // restricted rows, cols k=0..K-1
    int sY0 = c_s0[l] + jn * K;          // full set: row jn -> yl[n', k]
    int tid = threadIdx.x;
    int zl = tid >> 4;                   // 0..15
    int g0 = (tid & 15) * 2;             // 0..30
    float2 acc0 = make_float2(0.f, 0.f), acc1 = make_float2(0.f, 0.f);
    int nchunks = (K + 3) >> 2;
    for (int chunk = 0; chunk < nchunks; ++chunk) {
#pragma unroll
        for (int kw = 0; kw < 4; kw++) {           // stage X: 256 elems per kw
            int k = chunk * 4 + kw;
            if (k < K)
                Xs[kw][tid & 15][tid >> 4] =
                    xhat[(size_t)(sX0 + k) * 512 + (zh * 16 + (tid >> 4)) * 16 + (tid & 15)];
        }
#pragma unroll
        for (int it = 0; it < 8; it++) {           // stage Y: 512 elems per kw
            int kw = it >> 1;
            int fg = (it & 1) * 256 + tid;
            int k = chunk * 4 + kw;
            if (k < K)
                Ys[kw][fg >> 5][fg & 31] = yhat[(size_t)(sY0 + k) * 512 + fg];
        }
        __syncthreads();
#pragma unroll
        for (int kw = 0; kw < 4; kw++) {
            int k = chunk * 4 + kw;
            if (k < K) {
#pragma unroll
                for (int f = 0; f < 16; f++) {
                    float2 xv  = Xs[kw][f][zl];
                    float2 yv0 = Ys[kw][f][g0];
                    float2 yv1 = Ys[kw][f][g0 + 1];
                    acc0.x += xv.x * yv0.x + xv.y * yv0.y;
                    acc0.y += xv.y * yv0.x - xv.x * yv0.y;
                    acc1.x += xv.x * yv1.x + xv.y * yv1.y;
                    acc1.y += xv.y * yv1.x - xv.x * yv1.y;
                }
            }
        }
        __syncthreads();
    }
    int z0 = zh * 16 + zl;
    zbuf[(size_t)sp * 1024 + z0 * 32 + g0]     = acc0;
    zbuf[(size_t)sp * 1024 + z0 * 32 + g0 + 1] = acc1;
}

// ---------------- kE2: inverse Wigner + inverse 2D DFT (Hermitian) ----------
// grid 2048 = zg(1024) x b-half(2), block 256. 2 barriers.
__global__ __launch_bounds__(256) void kE2(const float2* __restrict__ zbuf,
                                           const float* __restrict__ wiT,
                                           const float* __restrict__ bias,
                                           float* __restrict__ out) {
    __shared__ float2 sz[NR];
    __shared__ float2 g1[8][129];    // [b-local][m*16+v]
    __shared__ float2 tw[16];        // e^{+2pi i k/16}
    int zg = blockIdx.x >> 1, bh = blockIdx.x & 1;
    int g = zg & 31;
    int tid = threadIdx.x;
    if (tid < 16) {
        float s, c;
        sincosf(2.0f * (float)M_PI * (float)tid / 16.0f, &s, &c);
        tw[tid] = make_float2(c, s);
    }
    for (int t = tid; t < NR; t += 256) sz[t] = zbuf[(size_t)t * 1024 + zg];
    __syncthreads();
    {   // phase 1: thread (b8, mm, vh): Wigner row m=mm, n-DFT quarter
        int b8 = tid & 7, mm = (tid >> 3) & 7, vh = tid >> 6;  // vh 0..3
        int b = bh * 8 + b8;
        float2 ff[15];
#pragma unroll
        for (int n = 0; n < 15; n++) {
            int nn = n - 7;
            int an = nn < 0 ? -nn : nn;
            int lmin = mm > an ? mm : an;
            float re = 0.f, im = 0.f;
            for (int l = lmin; l < 8; l++) {
                int K = 2 * l + 1;
                int sp = c_o[l] + mm * K + (nn + l);
                float w = wiT[sp * 16 + b];
                float2 v = sz[sp];
                re += w * v.x; im += w * v.y;
            }
            ff[n] = make_float2(re, im);
        }
#pragma unroll
        for (int j = 0; j < 4; j++) {
            int v = vh * 4 + j;
            float re = 0.f, im = 0.f;
#pragma unroll
            for (int n = 0; n < 15; n++) {
                float2 c = tw[((n - 7) * v) & 15];
                float2 a = ff[n];
                re += a.x * c.x - a.y * c.y;
                im += a.x * c.y + a.y * c.x;
            }
            g1[b8][mm * 16 + v] = make_float2(re, im);
        }
    }
    __syncthreads();
    {   // phase 2: thread (b8, u, vh): Hermitian-paired m-DFT, real output
        int b8 = tid & 7, u = (tid >> 3) & 15, vh = tid >> 7;  // vh 0..1
        int b = bh * 8 + b8;
        int v0 = vh * 8;
        float o[8];
#pragma unroll
        for (int j = 0; j < 8; j++) o[j] = g1[b8][v0 + j].x;   // m=0: h0 real
#pragma unroll
        for (int m = 1; m < 8; m++) {
            float2 c = tw[(m * u) & 15];
#pragma unroll
            for (int j = 0; j < 8; j++) {
                float2 a = g1[b8][m * 16 + v0 + j];
                o[j] += 2.f * (a.x * c.x - a.y * c.y);
            }
        }
        float bv = bias[g];
        float* ob = out + ((size_t)zg * 16 + b) * 256 + u * 16 + v0;
        *(float4*)&ob[0] = make_float4(o[0] + bv, o[1] + bv, o[2] + bv, o[3] + bv);
        *(float4*)&ob[4] = make_float4(o[4] + bv, o[5] + bv, o[6] + bv, o[7] + bv);
    }
}

extern "C" void kernel_launch(void* const* d_in, const int* in_sizes, int n_in,
                              void* d_out, int out_size, void* d_ws, size_t ws_size,
                              hipStream_t stream) {
    const float* x    = (const float*)d_in[0];
    const float* kern = (const float*)d_in[1];
    const float* bias = (const float*)d_in[2];
    const float* wf   = (const float*)d_in[3];
    const float* wi   = (const float*)d_in[4];
    const float* fre  = (const float*)d_in[5];
    const float* fim  = (const float*)d_in[6];
    float* out = (float*)d_out;

    // workspace layout (bytes):
    // xf2 @0        : 16384*120*8 = 15,728,640
    // xhat @15728640: 372*512*8   =  1,523,712
    // yhat @17252352: 680*512*8   =  2,785,280
    // zbuf @20037632: 372*1024*8  =  3,047,424
    // wfT  @23085056: 372*32*4    =     47,616
    // wiT  @23132672: 372*16*4    =     23,808
    char* ws = (char*)d_ws;
    float2* xf2  = (float2*)ws;
    float2* xhat = (float2*)(ws + 15728640);
    float2* yhat = (float2*)(ws + 17252352);
    float2* zbuf = (float2*)(ws + 20037632);
    float*  wfT  = (float*)(ws + 23085056);
    float*  wiT  = (float*)(ws + 23132672);

    A12<<<16384, 256, 0, stream>>>(x, xf2);
    kT2<<<70, 256, 0, stream>>>(wf, wi, wfT, wiT);
    kC<<<1360, 256, 0, stream>>>(kern, fre, fim, yhat);
    A3<<<1024, 256, 0, stream>>>(xf2, wfT, xhat);
    kD<<<744, 256, 0, stream>>>(xhat, yhat, zbuf);
    kE2<<<2048, 256, 0, stream>>>(zbuf, wiT, bias, out);
}

// Round 8
// 112.627 us; speedup vs baseline: 2.8653x; 1.1102x over previous
//
#include <hip/hip_runtime.h>
#include <math.h>

// SO(3) convolution, B_IN=16, B_OUT=8, BATCH=32, F_IN=16, F_OUT=32.
// Pipeline v7 (dense zero-padded inverse-Wigner, branch-free kE3):
//   A12: per-slice (z,f,b) partial 2D DFT 32x32 -> m=0..7 x n=-7..7 window
//   kT2: wfT[s'][32] transpose + DENSE wiTd[bh][l][b8][mm][16] (zero-padded)
//   kC : yhat = SCALING * kernel @ Fc  (full 680 set)
//   A3 : forward Wigner reduce over b -> xhat'[s'][zf] (m>=0 restricted set)
//   kD : per-s' complex GEMM zl = sum_{k,f} xhat*conj(yhat)
//   kE3: inverse Wigner (dense 8-trip l-loop, no divergence) + n-DFT +
//        Hermitian-paired m-DFT. grid 2048 = zg x b-half.

#define NS 680      // full spectral size
#define NR 372      // restricted (m>=0) spectral size
#define NP 24
#define NW 15
#define SCALING 0.14433756729740643f  // 1/sqrt(48)

__device__ __constant__ int c_s0[9] = {0, 1, 10, 35, 84, 165, 286, 455, 680};
__device__ __constant__ int c_o[9]  = {0, 1, 7, 22, 50, 95, 161, 252, 372};

// ---------------- A12: per-slice partial forward DFT ------------------------
__global__ __launch_bounds__(256) void A12(const float* __restrict__ x,
                                           float2* __restrict__ xf2) {
    __shared__ float  sx[32 * 36];
    __shared__ float2 st[32][8];
    __shared__ float2 tw[32];
    int slice = blockIdx.x;
    int tid = threadIdx.x;
    if (tid < 32) {
        float s, c;
        sincosf(-2.0f * (float)M_PI * (float)tid / 32.0f, &s, &c);
        tw[tid] = make_float2(c, s);
    }
    {
        const float4* xs = (const float4*)(x + (size_t)slice * 1024);
        float4 v4 = xs[tid];
        int u0 = tid >> 3, v0 = (tid & 7) * 4;
        *(float4*)&sx[u0 * 36 + v0] = v4;
    }
    __syncthreads();
    {
        int u = tid >> 3, n = tid & 7;
        float re = 0.f, im = 0.f;
#pragma unroll
        for (int v = 0; v < 32; v++) {
            float2 c = tw[(n * v) & 31];
            float xv = sx[u * 36 + v];
            re += xv * c.x; im += xv * c.y;
        }
        st[u][n] = make_float2(re, im);
    }
    __syncthreads();
    if (tid < 120) {
        int m = tid / 15, j = tid % 15, nn = j - 7;
        int an = nn < 0 ? -nn : nn;
        float sgn = nn < 0 ? -1.f : 1.f;
        float re = 0.f, im = 0.f;
#pragma unroll
        for (int u = 0; u < 32; u++) {
            float2 a = st[u][an];
            float ay = sgn * a.y;
            float2 c = tw[(m * u) & 31];
            re += a.x * c.x - ay * c.y;
            im += a.x * c.y + ay * c.x;
        }
        xf2[(size_t)slice * 120 + tid] = make_float2(re, im);
    }
}

// ---------------- kT2: wfT transpose + dense wiTd ---------------------------
__global__ void kT2(const float* __restrict__ wf, const float* __restrict__ wi,
                    float* __restrict__ wfT, float* __restrict__ wiTd) {
    int idx = blockIdx.x * blockDim.x + threadIdx.x;
    if (idx < NR * 32) {
        int sp = idx >> 5, b = idx & 31;
        int l = 0;
#pragma unroll
        for (int t = 1; t < 8; t++) if (sp >= c_o[t]) l = t;
        int K = 2 * l + 1, r = sp - c_o[l];
        int m = r / K, jn = r - m * K;
        int sf = c_s0[l] + (m + l) * K + jn;
        wfT[sp * 32 + b] = wf[b * NS + sf];
    } else {
        int j = idx - NR * 32;
        if (j >= 16384) return;
        int ni = j & 15, mm = (j >> 4) & 7, b8 = (j >> 7) & 7;
        int l = (j >> 10) & 7, bh = j >> 13;
        int nn = ni - 7;
        float v = 0.f;
        if (ni < 15 && mm <= l && nn >= -l && nn <= l) {
            int K = 2 * l + 1;
            v = wi[(bh * 8 + b8) * NS + c_s0[l] + (mm + l) * K + (nn + l)];
        }
        wiTd[j] = v;
    }
}

// ---------------- kC: yhat = (kernel*SCALING) @ Fc (full set) ---------------
__global__ void kC(const float* __restrict__ kern, const float* __restrict__ fre,
                   const float* __restrict__ fim, float2* __restrict__ yhat) {
    int idx = blockIdx.x * blockDim.x + threadIdx.x;
    if (idx >= NS * 512) return;
    int s = idx >> 9, fg = idx & 511;
    float re = 0.f, im = 0.f;
    for (int p = 0; p < NP; p++) {
        float kv = kern[fg * NP + p];
        re += kv * fre[p * NS + s];
        im += kv * fim[p * NS + s];
    }
    yhat[(size_t)s * 512 + fg] = make_float2(re * SCALING, im * SCALING);
}

// ---------------- A3: forward Wigner reduce over b (restricted) -------------
__global__ __launch_bounds__(256) void A3(const float2* __restrict__ xf2,
                                          const float* __restrict__ wfT,
                                          float2* __restrict__ xhat) {
    __shared__ float2 sxf[32 * 120];
    int zf = blockIdx.x >> 1, sh = blockIdx.x & 1;
    int tid = threadIdx.x;
    for (int t = tid; t < 32 * 120; t += 256)
        sxf[t] = xf2[(size_t)zf * (32 * 120) + t];
    __syncthreads();
    if (tid < 186) {
        int sp = sh * 186 + tid;
        int l = 0;
#pragma unroll
        for (int t = 1; t < 8; t++) if (sp >= c_o[t]) l = t;
        int K = 2 * l + 1, r = sp - c_o[l];
        int m = r / K, jn = r - m * K;
        int cell = m * 15 + (jn - l + 7);
        const float4* wp = (const float4*)(wfT + sp * 32);
        const float2* xp = sxf + cell;
        float re = 0.f, im = 0.f;
#pragma unroll
        for (int q = 0; q < 8; q++) {
            float4 w4 = wp[q];
            float2 v0 = xp[(q * 4 + 0) * 120];
            float2 v1 = xp[(q * 4 + 1) * 120];
            float2 v2 = xp[(q * 4 + 2) * 120];
            float2 v3 = xp[(q * 4 + 3) * 120];
            re += w4.x * v0.x + w4.y * v1.x + w4.z * v2.x + w4.w * v3.x;
            im += w4.x * v0.y + w4.y * v1.y + w4.z * v2.y + w4.w * v3.y;
        }
        xhat[(size_t)sp * 512 + zf] = make_float2(re, im);
    }
}

// ---------------- kD: per-s' complex GEMM -----------------------------------
__global__ __launch_bounds__(256) void kD(const float2* __restrict__ xhat,
                                          const float2* __restrict__ yhat,
                                          float2* __restrict__ zbuf) {
    __shared__ float2 Xs[4][16][18];
    __shared__ float2 Ys[4][16][34];
    int sp = 371 - (blockIdx.x >> 1);
    int zh = blockIdx.x & 1;
    int l = 0;
#pragma unroll
    for (int t = 1; t < 8; t++) if (sp >= c_o[t]) l = t;
    int K = 2 * l + 1, r = sp - c_o[l];
    int m = r / K, jn = r - m * K;
    int sX0 = c_o[l] + m * K;
    int sY0 = c_s0[l] + jn * K;
    int tid = threadIdx.x;
    int zl = tid >> 4;
    int g0 = (tid & 15) * 2;
    float2 acc0 = make_float2(0.f, 0.f), acc1 = make_float2(0.f, 0.f);
    int nchunks = (K + 3) >> 2;
    for (int chunk = 0; chunk < nchunks; ++chunk) {
#pragma unroll
        for (int kw = 0; kw < 4; kw++) {
            int k = chunk * 4 + kw;
            if (k < K)
                Xs[kw][tid & 15][tid >> 4] =
                    xhat[(size_t)(sX0 + k) * 512 + (zh * 16 + (tid >> 4)) * 16 + (tid & 15)];
        }
#pragma unroll
        for (int it = 0; it < 8; it++) {
            int kw = it >> 1;
            int fg = (it & 1) * 256 + tid;
            int k = chunk * 4 + kw;
            if (k < K)
                Ys[kw][fg >> 5][fg & 31] = yhat[(size_t)(sY0 + k) * 512 + fg];
        }
        __syncthreads();
#pragma unroll
        for (int kw = 0; kw < 4; kw++) {
            int k = chunk * 4 + kw;
            if (k < K) {
#pragma unroll
                for (int f = 0; f < 16; f++) {
                    float2 xv  = Xs[kw][f][zl];
                    float2 yv0 = Ys[kw][f][g0];
                    float2 yv1 = Ys[kw][f][g0 + 1];
                    acc0.x += xv.x * yv0.x + xv.y * yv0.y;
                    acc0.y += xv.y * yv0.x - xv.x * yv0.y;
                    acc1.x += xv.x * yv1.x + xv.y * yv1.y;
                    acc1.y += xv.y * yv1.x - xv.x * yv1.y;
                }
            }
        }
        __syncthreads();
    }
    int z0 = zh * 16 + zl;
    zbuf[(size_t)sp * 1024 + z0 * 32 + g0]     = acc0;
    zbuf[(size_t)sp * 1024 + z0 * 32 + g0 + 1] = acc1;
}

// ---------------- kE3: dense inverse Wigner + inverse 2D DFT ----------------
// grid 2048 = zg(1024) x b-half(2), block 256. 2 barriers, branch-free Wigner.
__global__ __launch_bounds__(256) void kE3(const float2* __restrict__ zbuf,
                                           const float* __restrict__ wiTd,
                                           const float* __restrict__ bias,
                                           float* __restrict__ out) {
    __shared__ float2 szp[384];      // [0..7]=0 pad, [8..379]=sz, [380..383]=0 pad
    __shared__ float2 g1[8][129];    // [b-local][m*16+v]
    __shared__ float2 tw[16];        // e^{+2pi i k/16}
    int zg = blockIdx.x >> 1, bh = blockIdx.x & 1;
    int g = zg & 31;
    int tid = threadIdx.x;
    if (tid < 16) {
        float s, c;
        sincosf(2.0f * (float)M_PI * (float)tid / 16.0f, &s, &c);
        tw[tid] = make_float2(c, s);
    }
    if (tid < 8)   szp[tid] = make_float2(0.f, 0.f);
    if (tid >= 252) szp[tid + 128] = make_float2(0.f, 0.f);   // 380..383
    for (int t = tid; t < NR; t += 256) szp[8 + t] = zbuf[(size_t)t * 1024 + zg];
    __syncthreads();
    if (tid < 128) {   // phase 1: (b8, mm, vh): dense Wigner row + half n-DFT
        int b8 = tid & 7, mm = (tid >> 3) & 7, vh = tid >> 6;  // vh 0..1
        const int co[8] = {0, 1, 7, 22, 50, 95, 161, 252};
        float2 ff[15];
#pragma unroll
        for (int n = 0; n < 15; n++) ff[n] = make_float2(0.f, 0.f);
#pragma unroll
        for (int l = 0; l < 8; l++) {
            const float4* wl = (const float4*)(wiTd + ((((bh * 8 + l) * 8 + b8) * 8 + mm) << 4));
            float4 w0 = wl[0], w1 = wl[1], w2 = wl[2], w3 = wl[3];
            float wreg[16] = {w0.x, w0.y, w0.z, w0.w, w1.x, w1.y, w1.z, w1.w,
                              w2.x, w2.y, w2.z, w2.w, w3.x, w3.y, w3.z, w3.w};
            int sp = 1 + co[l] + mm * (2 * l + 1) + l;   // szp index for ni=0
#pragma unroll
            for (int ni = 0; ni < 15; ni++) {
                float w = wreg[ni];
                float2 v = szp[sp + ni];
                ff[ni].x += w * v.x; ff[ni].y += w * v.y;
            }
        }
#pragma unroll
        for (int j = 0; j < 8; j++) {
            int v = vh * 8 + j;
            float re = 0.f, im = 0.f;
#pragma unroll
            for (int n = 0; n < 15; n++) {
                float2 c = tw[((n - 7) * v) & 15];
                float2 a = ff[n];
                re += a.x * c.x - a.y * c.y;
                im += a.x * c.y + a.y * c.x;
            }
            g1[b8][mm * 16 + v] = make_float2(re, im);
        }
    }
    __syncthreads();
    {   // phase 2: (b8, u, vh): Hermitian-paired m-DFT, real output
        int b8 = tid & 7, u = (tid >> 3) & 15, vh = tid >> 7;  // vh 0..1
        int b = bh * 8 + b8;
        int v0 = vh * 8;
        float o[8];
#pragma unroll
        for (int j = 0; j < 8; j++) o[j] = g1[b8][v0 + j].x;   // m=0 term
#pragma unroll
        for (int m = 1; m < 8; m++) {
            float2 c = tw[(m * u) & 15];
#pragma unroll
            for (int j = 0; j < 8; j++) {
                float2 a = g1[b8][m * 16 + v0 + j];
                o[j] += 2.f * (a.x * c.x - a.y * c.y);
            }
        }
        float bv = bias[g];
        float* ob = out + ((size_t)zg * 16 + b) * 256 + u * 16 + v0;
        *(float4*)&ob[0] = make_float4(o[0] + bv, o[1] + bv, o[2] + bv, o[3] + bv);
        *(float4*)&ob[4] = make_float4(o[4] + bv, o[5] + bv, o[6] + bv, o[7] + bv);
    }
}

extern "C" void kernel_launch(void* const* d_in, const int* in_sizes, int n_in,
                              void* d_out, int out_size, void* d_ws, size_t ws_size,
                              hipStream_t stream) {
    const float* x    = (const float*)d_in[0];
    const float* kern = (const float*)d_in[1];
    const float* bias = (const float*)d_in[2];
    const float* wf   = (const float*)d_in[3];
    const float* wi   = (const float*)d_in[4];
    const float* fre  = (const float*)d_in[5];
    const float* fim  = (const float*)d_in[6];
    float* out = (float*)d_out;

    // workspace layout (bytes):
    // xf2  @0        : 16384*120*8 = 15,728,640
    // xhat @15728640 : 372*512*8   =  1,523,712
    // yhat @17252352 : 680*512*8   =  2,785,280
    // zbuf @20037632 : 372*1024*8  =  3,047,424
    // wfT  @23085056 : 372*32*4    =     47,616
    // wiTd @23132672 : 16384*4     =     65,536
    char* ws = (char*)d_ws;
    float2* xf2  = (float2*)ws;
    float2* xhat = (float2*)(ws + 15728640);
    float2* yhat = (float2*)(ws + 17252352);
    float2* zbuf = (float2*)(ws + 20037632);
    float*  wfT  = (float*)(ws + 23085056);
    float*  wiTd = (float*)(ws + 23132672);

    A12<<<16384, 256, 0, stream>>>(x, xf2);
    kT2<<<111, 256, 0, stream>>>(wf, wi, wfT, wiTd);
    kC<<<1360, 256, 0, stream>>>(kern, fre, fim, yhat);
    A3<<<1024, 256, 0, stream>>>(xf2, wfT, xhat);
    kD<<<744, 256, 0, stream>>>(xhat, yhat, zbuf);
    kE3<<<2048, 256, 0, stream>>>(zbuf, wiTd, bias, out);
}